// Round 8
// baseline (2777.796 us; speedup 1.0000x reference)
//
#include <hip/hip_runtime.h>
#include <hip/hip_bf16.h>
#include <cstdint>

// SNN: Poisson encode (noise < x) -> [T=32] { h = sp@W1^T; v+=h; spike=(v>1); v-=spike; logits += spike@W2^T }
// B=8192, T=32, D_IN=784 (pad K to 800 = 25x32), D_H=100 (pad N to 128), D_OUT=10.
//
// v8: TOTAL fusion. Grid = 256 blocks (1/CU), block = 32 b-rows x 128 h x ALL t.
//   - x panel in registers (loaded once), noise double-buffered in registers,
//     prefetch t+1 issued before pack/MFMA of t (loads in flight across barriers:
//     raw s_barrier + lgkmcnt(0) only -- NO vmcnt drain).
//   - spikes ballot-packed to LDS sB[32][50] ushorts per t (v7 bit permutation).
//   - MFMA vs wf (L2-resident); IF state v/cnt in registers (C/D layout);
//     logits epilogue in-block. No H buffer, no scan kernel.

typedef __attribute__((ext_vector_type(8))) short bf16x8;
typedef __attribute__((ext_vector_type(4))) float f32x4;

#define D_IN 784
#define NB 8192
#define KT 25   // K tiles of 32 (800 padded)
#define NTL 8   // N tiles of 16 (128 padded)
#define DH 100
#define ROWS 32

// ---------------- K0: pack W1 into fragment-ready bf16 hi/lo ----------------
// Fragment f = (kt*8 + nt), stored as [f][hi(512 ushorts) | lo(512 ushorts)].
// B-slot(lane l, elem j): n = nt*16 + (l&15), i = kt*32 + (l>>4)*8 + j.
__global__ void prep_w1(const float* __restrict__ W1, unsigned short* __restrict__ wf) {
    int idx = blockIdx.x * 256 + threadIdx.x;           // 25*8*64 = 12800
    if (idx >= KT * NTL * 64) return;
    int l  = idx & 63;
    int nt = (idx >> 6) & 7;
    int kt = idx >> 9;
    int n  = nt * 16 + (l & 15);
    int i0 = kt * 32 + (l >> 4) * 8;
    size_t fbase = (size_t)(kt * 8 + nt) * 1024;
    #pragma unroll
    for (int j = 0; j < 8; ++j) {
        int i = i0 + j;
        float w = (n < DH && i < D_IN) ? W1[n * D_IN + i] : 0.f;
        uint32_t ub = __float_as_uint(w);
        uint32_t rh = ub + 0x7FFFu + ((ub >> 16) & 1u);
        unsigned short h = (unsigned short)(rh >> 16);
        float hf = __uint_as_float(((uint32_t)h) << 16);
        float resid = w - hf;
        uint32_t ul = __float_as_uint(resid);
        uint32_t rl = ul + 0x7FFFu + ((ul >> 16) & 1u);
        unsigned short lo = (unsigned short)(rl >> 16);
        wf[fbase + l * 8 + j]       = h;
        wf[fbase + 512 + l * 8 + j] = lo;
    }
}

// ---------------- K1: fully-fused SNN ----------------
// Pack bit permutation (v7-verbatim): pass p, wave w covers floats [1024p+256w, +256);
// ushort-group g = 64p + 16w + u (u=lane&15), row = g/49, colu = g%49;
// stored bit q within ushort <-> float offset f: q = 4*(f&3) + (f>>2).
// A-frag expand (v7-verbatim): lg = lane>>4, qe0 = (lg&1)*2 + (lg>>1)*16;
// dword d: qe = qe0 + (d&1)*8 + (d>>1); bits {qe, qe+4}.
__global__ __launch_bounds__(256, 1) void snn_all(const float* __restrict__ x,
                                                  const float* __restrict__ noise,
                                                  const unsigned short* __restrict__ wf,
                                                  const float* __restrict__ W2,
                                                  float* __restrict__ out) {
    __shared__ __align__(4) unsigned short sB[ROWS * 50];   // 3.2KB spike bits (1 t)
    __shared__ float w2s[1000];
    __shared__ float cbuf[ROWS][104];
    const int tid  = threadIdx.x;
    const int lane = tid & 63;
    const int wave = tid >> 6;
    const int b0   = blockIdx.x * ROWS;
    const int Mt   = wave & 1;         // M-tile (rows Mt*16 .. +15)
    const int Ng   = wave >> 1;        // N-group (tiles Ng*4 .. +3)

    if (tid < ROWS) sB[tid * 50 + 49] = 0;                 // k-pad (bits 784..799)
    for (int i = tid; i < 1000; i += 256) w2s[i] = W2[i];

    // x panel in registers (once)
    float4 xr[25];
    const float* xb = x + (size_t)b0 * D_IN;
    #pragma unroll
    for (int p = 0; p < 25; ++p) {
        int f4 = p * 256 + tid;
        if (p == 24 && tid >= 128) f4 = tid;               // clamp (lanes unused in pack)
        xr[p] = *reinterpret_cast<const float4*>(xb + (size_t)f4 * 4);
    }
    const float* nbase  = noise + (size_t)b0 * D_IN;
    const size_t tstride = (size_t)NB * D_IN;

    float4 na[25], nb_[25];
    #pragma unroll
    for (int p = 0; p < 25; ++p) {                         // prefetch t=0
        int f4 = p * 256 + tid;
        if (p == 24 && tid >= 128) f4 = tid;
        na[p] = *reinterpret_cast<const float4*>(nbase + (size_t)f4 * 4);
    }

    f32x4 v[4], cnt[4];
    #pragma unroll
    for (int nt = 0; nt < 4; ++nt) { v[nt] = (f32x4){0,0,0,0}; cnt[nt] = (f32x4){0,0,0,0}; }

    const int u    = lane & 15;
    const int lg   = lane >> 4;
    const int qe0  = (lg & 1) * 2 + (lg >> 1) * 16;
    const int arow = (Mt * 16 + (lane & 15)) * 25;
    const uint32_t* s32 = reinterpret_cast<const uint32_t*>(sB);

    auto STEP = [&](int t, float4 (&CUR)[25], float4 (&NXT)[25]) {
        if (t < 31) {                                      // prefetch t+1 FIRST
            const float* np_ = nbase + (size_t)(t + 1) * tstride;
            #pragma unroll
            for (int p = 0; p < 25; ++p) {
                int f4 = p * 256 + tid;
                if (p == 24 && tid >= 128) f4 = tid;
                NXT[p] = *reinterpret_cast<const float4*>(np_ + (size_t)f4 * 4);
            }
        }
        // pack CUR vs xr -> sB
        #pragma unroll
        for (int p = 0; p < 25; ++p) {
            const unsigned long long m0 = __ballot(CUR[p].x < xr[p].x);
            const unsigned long long m1 = __ballot(CUR[p].y < xr[p].y);
            const unsigned long long m2 = __ballot(CUR[p].z < xr[p].z);
            const unsigned long long m3 = __ballot(CUR[p].w < xr[p].w);
            const int g = p * 64 + wave * 16 + u;
            if (lane < 16 && g < 1568) {
                const uint32_t vv = (uint32_t)((m0 >> (4 * u)) & 15ull)
                                  | ((uint32_t)((m1 >> (4 * u)) & 15ull) << 4)
                                  | ((uint32_t)((m2 >> (4 * u)) & 15ull) << 8)
                                  | ((uint32_t)((m3 >> (4 * u)) & 15ull) << 12);
                const uint32_t row = ((uint32_t)g * 42800u) >> 21;   // g/49 exact
                const int colu = g - (int)row * 49;
                sB[row * 50 + colu] = (unsigned short)vv;
            }
        }
        // LDS writes visible; do NOT drain vmcnt (prefetch stays in flight)
        asm volatile("s_waitcnt lgkmcnt(0)\n\ts_barrier" ::: "memory");

        f32x4 acc[4];
        #pragma unroll
        for (int nt = 0; nt < 4; ++nt) acc[nt] = (f32x4){0,0,0,0};
        #pragma unroll
        for (int kt = 0; kt < KT; ++kt) {
            const uint32_t g = s32[arow + kt];
            union { uint32_t uu[4]; bf16x8 vv; } pk;
            #pragma unroll
            for (int d = 0; d < 4; ++d) {
                const int qe = qe0 + (d & 1) * 8 + (d >> 1);
                pk.uu[d] = ((g >> qe) & 1u) * 0x3F80u
                         | ((g >> (qe + 4)) & 1u) * 0x3F800000u;
            }
            #pragma unroll
            for (int nt = 0; nt < 4; ++nt) {
                const size_t fo = (size_t)(kt * 8 + Ng * 4 + nt) * 1024 + lane * 8;
                const bf16x8 bhi = *reinterpret_cast<const bf16x8*>(wf + fo);
                const bf16x8 blo = *reinterpret_cast<const bf16x8*>(wf + fo + 512);
                acc[nt] = __builtin_amdgcn_mfma_f32_16x16x32_bf16(pk.vv, bhi, acc[nt], 0, 0, 0);
                acc[nt] = __builtin_amdgcn_mfma_f32_16x16x32_bf16(pk.vv, blo, acc[nt], 0, 0, 0);
            }
        }
        // IF update (exact reference semantics, f32)
        #pragma unroll
        for (int nt = 0; nt < 4; ++nt)
            #pragma unroll
            for (int r = 0; r < 4; ++r) {
                const float vv = v[nt][r] + acc[nt][r];
                const float s = (vv - 1.0f > 0.0f) ? 1.0f : 0.0f;
                v[nt][r] = vv - s;
                cnt[nt][r] += s;
            }
        // protect sB before next t's pack; ds_reads already consumed
        asm volatile("s_barrier" ::: "memory");
    };

    for (int tt = 0; tt < 16; ++tt) {
        STEP(2 * tt,     na,  nb_);
        STEP(2 * tt + 1, nb_, na);
    }

    // epilogue: cnt -> cbuf, logits = cnt @ W2^T
    #pragma unroll
    for (int nt = 0; nt < 4; ++nt) {
        const int col = (Ng * 4 + nt) * 16 + (lane & 15);
        if (col < DH) {
            #pragma unroll
            for (int r = 0; r < 4; ++r)
                cbuf[Mt * 16 + lg * 4 + r][col] = cnt[nt][r];
        }
    }
    __syncthreads();
    #pragma unroll
    for (int pp = 0; pp < 2; ++pp) {
        const int idx = pp * 256 + tid;
        if (idx < 320) {
            const int o = idx >> 5, row = idx & 31;
            float s = 0.f;
            for (int hh = 0; hh < DH; ++hh) s += cbuf[row][hh] * w2s[o * DH + hh];
            out[(size_t)(b0 + row) * 10 + o] = s;
        }
    }
}

extern "C" void kernel_launch(void* const* d_in, const int* in_sizes, int n_in,
                              void* d_out, int out_size, void* d_ws, size_t ws_size,
                              hipStream_t stream) {
    const float* x     = (const float*)d_in[0];   // [8192,784]
    const float* noise = (const float*)d_in[1];   // [32,8192,784]
    const float* W1    = (const float*)d_in[2];   // [100,784]
    const float* W2    = (const float*)d_in[3];   // [10,100]
    float* out = (float*)d_out;                   // [8192,10]

    unsigned short* wf = (unsigned short*)d_ws;   // 400 KB W1 frags

    prep_w1<<<50, 256, 0, stream>>>(W1, wf);
    snn_all<<<256, 256, 0, stream>>>(x, noise, wf, W2, out);
}

// Round 9
// 856.750 us; speedup vs baseline: 3.2422x; 3.2422x over previous
//
#include <hip/hip_runtime.h>
#include <hip/hip_bf16.h>
#include <cstdint>

// SNN: Poisson encode (noise < x) -> [T=32] { h = sp@W1^T; v+=h; spike=(v>1); v-=spike; logits += spike@W2^T }
// B=8192, T=32, D_IN=784 (pad K to 800 = 25x32), D_H=100 (pad N to 128), D_OUT=10.
//
// v9: t-fused like v8 but spill-free and L2-rate-feasible.
//   Grid 256 x 512thr. Block = 32 b-rows x 128 h x ALL t. Wave w = nt tile w (16 h),
//   both 16-row M-tiles (mt=2 -> wf traffic 400KB/block/t = 40 B/cy/CU < L2 share).
//   Staging: x 13xfloat4 + noise dbuf 2x13 = 156 VGPRs (fits; v8's 300 spilled).
//   Per t: prefetch t+1 -> pack bits to LDS (v7 mapping) -> raw barrier (NO vmcnt
//   drain) -> expand+MFMA vs wf (L2) -> IF update in regs -> barrier.
//   Epilogue: cnt @ W2^T in-block. No H buffer, no scan kernel.

typedef __attribute__((ext_vector_type(8))) short bf16x8;
typedef __attribute__((ext_vector_type(4))) float f32x4;

#define D_IN 784
#define NB 8192
#define KT 25   // K tiles of 32 (800 padded)
#define NTL 8   // N tiles of 16 (128 padded)
#define DH 100
#define ROWS 32

// ---------------- K0: pack W1 into fragment-ready bf16 hi/lo ----------------
// Fragment f = (kt*8 + nt), stored as [f][hi(512 ushorts) | lo(512 ushorts)].
// B-slot(lane l, elem j): n = nt*16 + (l&15), i = kt*32 + (l>>4)*8 + j.
__global__ void prep_w1(const float* __restrict__ W1, unsigned short* __restrict__ wf) {
    int idx = blockIdx.x * 256 + threadIdx.x;           // 25*8*64 = 12800
    if (idx >= KT * NTL * 64) return;
    int l  = idx & 63;
    int nt = (idx >> 6) & 7;
    int kt = idx >> 9;
    int n  = nt * 16 + (l & 15);
    int i0 = kt * 32 + (l >> 4) * 8;
    size_t fbase = (size_t)(kt * 8 + nt) * 1024;
    #pragma unroll
    for (int j = 0; j < 8; ++j) {
        int i = i0 + j;
        float w = (n < DH && i < D_IN) ? W1[n * D_IN + i] : 0.f;
        uint32_t ub = __float_as_uint(w);
        uint32_t rh = ub + 0x7FFFu + ((ub >> 16) & 1u);
        unsigned short h = (unsigned short)(rh >> 16);
        float hf = __uint_as_float(((uint32_t)h) << 16);
        float resid = w - hf;
        uint32_t ul = __float_as_uint(resid);
        uint32_t rl = ul + 0x7FFFu + ((ul >> 16) & 1u);
        unsigned short lo = (unsigned short)(rl >> 16);
        wf[fbase + l * 8 + j]       = h;
        wf[fbase + 512 + l * 8 + j] = lo;
    }
}

// ---------------- K1: fully-fused SNN (v9) ----------------
// Pack mapping (v7-verbatim, 512-thr indexing): panel = 32 rows x 196 float4 = 6272 f4.
// Pass p: thread handles f4 = p*512 + tid (p=12: tid<128). ushort-group
// g = p*128 + wave*16 + u (u = lane&15), row = g/49, colu = g%49;
// stored bit q <-> float offset f within group: q = 4*(f&3) + (f>>2).
// Expand (v7-verbatim): lg = lane>>4, qe0 = (lg&1)*2 + (lg>>1)*16;
// dword d: qe = qe0 + (d&1)*8 + (d>>1); bits {qe, qe+4}.
__global__ __launch_bounds__(512, 2) void snn_all(const float* __restrict__ x,
                                                  const float* __restrict__ noise,
                                                  const unsigned short* __restrict__ wf,
                                                  const float* __restrict__ W2,
                                                  float* __restrict__ out) {
    __shared__ __align__(4) unsigned short sB[ROWS * 50];   // 3.2KB spike bits (1 t)
    __shared__ float w2s[1000];
    __shared__ float cbuf[ROWS][132];
    const int tid  = threadIdx.x;
    const int lane = tid & 63;
    const int wave = tid >> 6;         // = nt tile 0..7
    const int b0   = blockIdx.x * ROWS;

    if (tid < ROWS) sB[tid * 50 + 49] = 0;                 // k-pad (bits 784..799)
    for (int i = tid; i < 1000; i += 512) w2s[i] = W2[i];

    // per-thread float offsets (13 float4; p=12 clamped for tid>=128, unused by store guard)
    int foff[13];
    #pragma unroll
    for (int p = 0; p < 13; ++p) {
        int f4 = p * 512 + tid;
        if (p == 12 && tid >= 128) f4 = tid;
        foff[p] = f4 * 4;
    }

    const float* xb     = x + (size_t)b0 * D_IN;
    const float* nbase  = noise + (size_t)b0 * D_IN;
    const size_t tstride = (size_t)NB * D_IN;

    float4 xr[13], na[13], nb_[13];
    #pragma unroll
    for (int p = 0; p < 13; ++p) {
        xr[p] = *reinterpret_cast<const float4*>(xb + foff[p]);
        na[p] = *reinterpret_cast<const float4*>(nbase + foff[p]);   // t=0 prefetch
    }

    f32x4 v[2], cnt[2];
    #pragma unroll
    for (int m = 0; m < 2; ++m) { v[m] = (f32x4){0,0,0,0}; cnt[m] = (f32x4){0,0,0,0}; }

    const int u   = lane & 15;
    const int lg  = lane >> 4;
    const int qe0 = (lg & 1) * 2 + (lg >> 1) * 16;
    const uint32_t* s32 = reinterpret_cast<const uint32_t*>(sB);

    auto STEP = [&](int t, float4 (&CUR)[13], float4 (&NXT)[13]) {
        if (t < 31) {                                      // prefetch t+1 FIRST
            const float* np_ = nbase + (size_t)(t + 1) * tstride;
            #pragma unroll
            for (int p = 0; p < 13; ++p)
                NXT[p] = *reinterpret_cast<const float4*>(np_ + foff[p]);
        }
        // ---- pack CUR vs xr -> sB ----
        #pragma unroll
        for (int p = 0; p < 13; ++p) {
            const unsigned long long m0 = __ballot(CUR[p].x < xr[p].x);
            const unsigned long long m1 = __ballot(CUR[p].y < xr[p].y);
            const unsigned long long m2 = __ballot(CUR[p].z < xr[p].z);
            const unsigned long long m3 = __ballot(CUR[p].w < xr[p].w);
            const int g = p * 128 + wave * 16 + u;
            if (lane < 16 && g < 1568) {
                const uint32_t vv = (uint32_t)((m0 >> (4 * u)) & 15ull)
                                  | ((uint32_t)((m1 >> (4 * u)) & 15ull) << 4)
                                  | ((uint32_t)((m2 >> (4 * u)) & 15ull) << 8)
                                  | ((uint32_t)((m3 >> (4 * u)) & 15ull) << 12);
                const uint32_t row = ((uint32_t)g * 42800u) >> 21;   // g/49 exact
                const int colu = g - (int)row * 49;
                sB[row * 50 + colu] = (unsigned short)vv;
            }
        }
        // LDS writes visible; prefetch stays in flight (no vmcnt drain)
        asm volatile("s_waitcnt lgkmcnt(0)\n\ts_barrier" ::: "memory");

        // ---- bit-GEMM: wave = nt tile, mt = 0,1 ----
        f32x4 acc0 = (f32x4){0,0,0,0}, acc1 = (f32x4){0,0,0,0};
        #pragma unroll
        for (int kt = 0; kt < KT; ++kt) {
            const uint32_t g0 = s32[u * 25 + kt];
            const uint32_t g1 = s32[(u + 16) * 25 + kt];
            union { uint32_t uu[4]; bf16x8 vv; } pk0, pk1;
            #pragma unroll
            for (int d = 0; d < 4; ++d) {
                const int qe = qe0 + (d & 1) * 8 + (d >> 1);
                pk0.uu[d] = ((g0 >> qe) & 1u) * 0x3F80u | ((g0 >> (qe + 4)) & 1u) * 0x3F800000u;
                pk1.uu[d] = ((g1 >> qe) & 1u) * 0x3F80u | ((g1 >> (qe + 4)) & 1u) * 0x3F800000u;
            }
            const size_t fo = (size_t)(kt * 8 + wave) * 1024 + lane * 8;
            const bf16x8 bhi = *reinterpret_cast<const bf16x8*>(wf + fo);
            const bf16x8 blo = *reinterpret_cast<const bf16x8*>(wf + fo + 512);
            acc0 = __builtin_amdgcn_mfma_f32_16x16x32_bf16(pk0.vv, bhi, acc0, 0, 0, 0);
            acc0 = __builtin_amdgcn_mfma_f32_16x16x32_bf16(pk0.vv, blo, acc0, 0, 0, 0);
            acc1 = __builtin_amdgcn_mfma_f32_16x16x32_bf16(pk1.vv, bhi, acc1, 0, 0, 0);
            acc1 = __builtin_amdgcn_mfma_f32_16x16x32_bf16(pk1.vv, blo, acc1, 0, 0, 0);
        }
        // ---- IF update (exact reference semantics, f32) ----
        #pragma unroll
        for (int r = 0; r < 4; ++r) {
            float v0 = v[0][r] + acc0[r];
            float s0 = (v0 - 1.0f > 0.0f) ? 1.0f : 0.0f;
            v[0][r] = v0 - s0;  cnt[0][r] += s0;
            float v1 = v[1][r] + acc1[r];
            float s1 = (v1 - 1.0f > 0.0f) ? 1.0f : 0.0f;
            v[1][r] = v1 - s1;  cnt[1][r] += s1;
        }
        // protect sB before next t's pack (ds_reads already consumed)
        asm volatile("s_barrier" ::: "memory");
    };

    for (int tt = 0; tt < 16; ++tt) {
        STEP(2 * tt,     na,  nb_);
        STEP(2 * tt + 1, nb_, na);
    }

    // ---- epilogue: cnt -> cbuf, logits = cnt @ W2^T ----
    // C/D layout: col = lane&15 (h = wave*16+u), row = lg*4 + r (+ 16*mt)
    #pragma unroll
    for (int m = 0; m < 2; ++m)
        #pragma unroll
        for (int r = 0; r < 4; ++r)
            cbuf[m * 16 + lg * 4 + r][wave * 16 + u] = cnt[m][r];
    __syncthreads();
    {
        const int row = tid >> 4, o = tid & 15;
        if (o < 10) {
            float s = 0.f;
            for (int hh = 0; hh < DH; ++hh) s += cbuf[row][hh] * w2s[o * DH + hh];
            out[(size_t)(b0 + row) * 10 + o] = s;
        }
    }
}

extern "C" void kernel_launch(void* const* d_in, const int* in_sizes, int n_in,
                              void* d_out, int out_size, void* d_ws, size_t ws_size,
                              hipStream_t stream) {
    const float* x     = (const float*)d_in[0];   // [8192,784]
    const float* noise = (const float*)d_in[1];   // [32,8192,784]
    const float* W1    = (const float*)d_in[2];   // [100,784]
    const float* W2    = (const float*)d_in[3];   // [10,100]
    float* out = (float*)d_out;                   // [8192,10]

    unsigned short* wf = (unsigned short*)d_ws;   // 400 KB W1 frags

    prep_w1<<<50, 256, 0, stream>>>(W1, wf);
    snn_all<<<256, 512, 0, stream>>>(x, noise, wf, W2, out);
}

// Round 10
// 438.325 us; speedup vs baseline: 6.3373x; 1.9546x over previous
//
#include <hip/hip_runtime.h>
#include <hip/hip_bf16.h>
#include <cstdint>

// SNN: Poisson encode (noise < x) -> [T=32] { h = sp@W1^T; v+=h; spike=(v>1); v-=spike; logits += spike@W2^T }
// B=8192, T=32, D_IN=784 (pad K to 800 = 25x32), D_H=100 (pad N to 128), D_OUT=10.
//
// v10: t-fused, spill-free, kt-OUTER over groups of G=4 t-steps.
//   Grid 256 x 512thr (1 block/CU). Block = 32 b-rows x 128 h x ALL t.
//   Per group tg (4 t's): 4 chunks of { issue 13 noise loads for next group's
//   sub-t c -> MFMA a kt-chunk over ALL 4 current t's (one wf fragment read per
//   kt serves 4 t's -> wf traffic /4 vs v9) -> compare+ballot+pack into
//   sB[nxt][c] }. IF update in registers, ONE __syncthreads per group.
//   VGPR budget: launch_bounds(512,1) -> 256; live ~190 (xr 52 + tmp 52 +
//   acc 32 + v/cnt 16 + misc). v9's (512,2) capped at 128 -> spilled.

typedef __attribute__((ext_vector_type(8))) short bf16x8;
typedef __attribute__((ext_vector_type(4))) float f32x4;

#define D_IN 784
#define NB 8192
#define KT 25   // K tiles of 32 (800 padded)
#define DH 100
#define ROWS 32

// ---------------- K0: pack W1 into fragment-ready bf16 hi/lo ----------------
// Fragment f = (kt*8 + nt), stored as [f][hi(512 ushorts) | lo(512 ushorts)].
// B-slot(lane l, elem j): n = nt*16 + (l&15), i = kt*32 + (l>>4)*8 + j.
__global__ void prep_w1(const float* __restrict__ W1, unsigned short* __restrict__ wf) {
    int idx = blockIdx.x * 256 + threadIdx.x;           // 25*8*64 = 12800
    if (idx >= KT * 8 * 64) return;
    int l  = idx & 63;
    int nt = (idx >> 6) & 7;
    int kt = idx >> 9;
    int n  = nt * 16 + (l & 15);
    int i0 = kt * 32 + (l >> 4) * 8;
    size_t fbase = (size_t)(kt * 8 + nt) * 1024;
    #pragma unroll
    for (int j = 0; j < 8; ++j) {
        int i = i0 + j;
        float w = (n < DH && i < D_IN) ? W1[n * D_IN + i] : 0.f;
        uint32_t ub = __float_as_uint(w);
        uint32_t rh = ub + 0x7FFFu + ((ub >> 16) & 1u);
        unsigned short h = (unsigned short)(rh >> 16);
        float hf = __uint_as_float(((uint32_t)h) << 16);
        float resid = w - hf;
        uint32_t ul = __float_as_uint(resid);
        uint32_t rl = ul + 0x7FFFu + ((ul >> 16) & 1u);
        unsigned short lo = (unsigned short)(rl >> 16);
        wf[fbase + l * 8 + j]       = h;
        wf[fbase + 512 + l * 8 + j] = lo;
    }
}

// ---------------- K1: fully-fused SNN (v10) ----------------
// Pack mapping (v9-verbatim): pass p, thread handles f4 = p*512+tid (p=12: tid<128);
// ushort-group gg = p*128 + wave*16 + u (u=lane&15), row = gg/49, colu = gg%49;
// stored bit q <-> float offset f within group: q = 4*(f&3) + (f>>2).
// Expand (v9-verbatim): lg = lane>>4, qe0 = (lg&1)*2 + (lg>>1)*16;
// dword d: qe = qe0 + (d&1)*8 + (d>>1); bits {qe, qe+4}.
__global__ __launch_bounds__(512, 1) void snn_all(const float* __restrict__ x,
                                                  const float* __restrict__ noise,
                                                  const unsigned short* __restrict__ wf,
                                                  const float* __restrict__ W2,
                                                  float* __restrict__ out) {
    __shared__ __align__(4) unsigned short sB[2][4][ROWS * 50];  // 25.6KB (dbuf x 4 t)
    __shared__ float w2s[1000];
    __shared__ float cbuf[ROWS][132];
    const int tid  = threadIdx.x;
    const int lane = tid & 63;
    const int wave = tid >> 6;         // = nt tile 0..7 (16 h each)
    const int b0   = blockIdx.x * ROWS;
    const int u    = lane & 15;
    const int lg   = lane >> 4;
    const int qe0  = (lg & 1) * 2 + (lg >> 1) * 16;

    unsigned short* sbf = &sB[0][0][0];
    if (tid < 256) sbf[(tid >> 5) * 1600 + (tid & 31) * 50 + 49] = 0;  // k-pad all 8 tiles
    for (int i = tid; i < 1000; i += 512) w2s[i] = W2[i];

    int foff[13];
    #pragma unroll
    for (int p = 0; p < 13; ++p) {
        int f4 = p * 512 + tid;
        if (p == 12 && tid >= 128) f4 = tid;      // clamp; stores guarded by gg<1568
        foff[p] = f4 * 4;
    }

    const float* xb     = x + (size_t)b0 * D_IN;
    const float* nbase  = noise + (size_t)b0 * D_IN;
    const size_t tstride = (size_t)NB * D_IN;

    float4 xr[13];
    #pragma unroll
    for (int p = 0; p < 13; ++p) xr[p] = *reinterpret_cast<const float4*>(xb + foff[p]);

    float4 tmp[13];                                // transient load buffer
    auto LOAD = [&](int t) {
        const float* np_ = nbase + (size_t)t * tstride;
        #pragma unroll
        for (int p = 0; p < 13; ++p)
            tmp[p] = *reinterpret_cast<const float4*>(np_ + foff[p]);
    };
    auto PACK = [&](int buf, int g) {
        unsigned short* dst = sbf + (buf * 4 + g) * 1600;
        #pragma unroll
        for (int p = 0; p < 13; ++p) {
            const unsigned long long m0 = __ballot(tmp[p].x < xr[p].x);
            const unsigned long long m1 = __ballot(tmp[p].y < xr[p].y);
            const unsigned long long m2 = __ballot(tmp[p].z < xr[p].z);
            const unsigned long long m3 = __ballot(tmp[p].w < xr[p].w);
            const int gg = p * 128 + wave * 16 + u;
            if (lane < 16 && gg < 1568) {
                const uint32_t vv = (uint32_t)((m0 >> (4 * u)) & 15ull)
                                  | ((uint32_t)((m1 >> (4 * u)) & 15ull) << 4)
                                  | ((uint32_t)((m2 >> (4 * u)) & 15ull) << 8)
                                  | ((uint32_t)((m3 >> (4 * u)) & 15ull) << 12);
                const uint32_t row = ((uint32_t)gg * 42800u) >> 21;   // gg/49 exact
                dst[row * 50 + (gg - (int)row * 49)] = (unsigned short)vv;
            }
        }
    };

    // prologue: group 0 (t=0..3) into buf 0
    #pragma unroll
    for (int g = 0; g < 4; ++g) { LOAD(g); PACK(0, g); }

    f32x4 v[2], cnt[2];
    #pragma unroll
    for (int m = 0; m < 2; ++m) { v[m] = (f32x4){0,0,0,0}; cnt[m] = (f32x4){0,0,0,0}; }
    __syncthreads();

    for (int tg = 0; tg < 8; ++tg) {
        const int cur = tg & 1;
        f32x4 acc[4][2];
        #pragma unroll
        for (int g = 0; g < 4; ++g) { acc[g][0] = (f32x4){0,0,0,0}; acc[g][1] = (f32x4){0,0,0,0}; }

        // 4 chunks: LOAD(next sub-t) -> MFMA kt-chunk (all 4 current t's) -> PACK
        #pragma unroll
        for (int c = 0; c < 4; ++c) {
            const bool pre = (tg < 7);
            if (pre) LOAD(4 * (tg + 1) + c);
            const int lo = (c == 0) ? 0 : 1 + 6 * c;          // {0,7,13,19}
            const int hi = 1 + 6 * (c + 1);                    // {7,13,19,25}
            for (int kt = lo; kt < hi; ++kt) {
                const size_t fo = (size_t)(kt * 8 + wave) * 1024 + lane * 8;
                const bf16x8 bhi = *reinterpret_cast<const bf16x8*>(wf + fo);
                const bf16x8 blo = *reinterpret_cast<const bf16x8*>(wf + fo + 512);
                #pragma unroll
                for (int g = 0; g < 4; ++g) {
                    const uint32_t* s32 = reinterpret_cast<const uint32_t*>(sbf + (cur * 4 + g) * 1600);
                    const uint32_t g0 = s32[u * 25 + kt];
                    const uint32_t g1 = s32[(u + 16) * 25 + kt];
                    union { uint32_t uu[4]; bf16x8 vv; } pk0, pk1;
                    #pragma unroll
                    for (int d = 0; d < 4; ++d) {
                        const int qe = qe0 + (d & 1) * 8 + (d >> 1);
                        pk0.uu[d] = ((g0 >> qe) & 1u) * 0x3F80u | ((g0 >> (qe + 4)) & 1u) * 0x3F800000u;
                        pk1.uu[d] = ((g1 >> qe) & 1u) * 0x3F80u | ((g1 >> (qe + 4)) & 1u) * 0x3F800000u;
                    }
                    acc[g][0] = __builtin_amdgcn_mfma_f32_16x16x32_bf16(pk0.vv, bhi, acc[g][0], 0, 0, 0);
                    acc[g][0] = __builtin_amdgcn_mfma_f32_16x16x32_bf16(pk0.vv, blo, acc[g][0], 0, 0, 0);
                    acc[g][1] = __builtin_amdgcn_mfma_f32_16x16x32_bf16(pk1.vv, bhi, acc[g][1], 0, 0, 0);
                    acc[g][1] = __builtin_amdgcn_mfma_f32_16x16x32_bf16(pk1.vv, blo, acc[g][1], 0, 0, 0);
                }
            }
            if (pre) PACK(cur ^ 1, c);
        }

        // IF update, sequential over the 4 t's (exact reference semantics)
        #pragma unroll
        for (int g = 0; g < 4; ++g)
            #pragma unroll
            for (int m = 0; m < 2; ++m)
                #pragma unroll
                for (int r = 0; r < 4; ++r) {
                    const float vv = v[m][r] + acc[g][m][r];
                    const float s = (vv - 1.0f > 0.0f) ? 1.0f : 0.0f;
                    v[m][r] = vv - s;
                    cnt[m][r] += s;
                }
        __syncthreads();   // sB[cur] reads done; sB[nxt] writes visible
    }

    // ---- epilogue: cnt -> cbuf, logits = cnt @ W2^T ----
    // C/D layout: col = lane&15 (h = wave*16+u), row = m*16 + lg*4 + r
    #pragma unroll
    for (int m = 0; m < 2; ++m)
        #pragma unroll
        for (int r = 0; r < 4; ++r)
            cbuf[m * 16 + lg * 4 + r][wave * 16 + u] = cnt[m][r];
    __syncthreads();
    {
        const int row = tid >> 4, o = tid & 15;
        if (o < 10) {
            float s = 0.f;
            for (int hh = 0; hh < DH; ++hh) s += cbuf[row][hh] * w2s[o * DH + hh];
            out[(size_t)(b0 + row) * 10 + o] = s;
        }
    }
}

extern "C" void kernel_launch(void* const* d_in, const int* in_sizes, int n_in,
                              void* d_out, int out_size, void* d_ws, size_t ws_size,
                              hipStream_t stream) {
    const float* x     = (const float*)d_in[0];   // [8192,784]
    const float* noise = (const float*)d_in[1];   // [32,8192,784]
    const float* W1    = (const float*)d_in[2];   // [100,784]
    const float* W2    = (const float*)d_in[3];   // [10,100]
    float* out = (float*)d_out;                   // [8192,10]

    unsigned short* wf = (unsigned short*)d_ws;   // 400 KB W1 frags

    prep_w1<<<50, 256, 0, stream>>>(W1, wf);
    snn_all<<<256, 512, 0, stream>>>(x, noise, wf, W2, out);
}